// Round 2
// baseline (3400.346 us; speedup 1.0000x reference)
//
#include <hip/hip_runtime.h>
#include <hip/hip_bf16.h>
#include <stdint.h>

// Keep mul+add separate (XLA/numpy do not contract across ops). Perf-critical
// loops use explicit fmaf(), which stays fused regardless of this pragma.
#pragma clang fp contract(off)

#define PI_F     3.14159265358979323846f   // rounds to 0x40490FDB (f32 np.pi)
#define TWO_PI_F 6.28318530717958647692f   // 0x40C90FDB

// ============================ threefry2x32 ==================================
__device__ __forceinline__ void tfround(uint32_t &x0, uint32_t &x1, const int r) {
  x0 += x1;
  x1 = (x1 << r) | (x1 >> (32 - r));
  x1 ^= x0;
}

__device__ __forceinline__ void threefry2x32(uint32_t k0, uint32_t k1,
                                             uint32_t &x0, uint32_t &x1) {
  uint32_t k2 = k0 ^ k1 ^ 0x1BD11BDAu;
  x0 += k0; x1 += k1;
  tfround(x0,x1,13); tfround(x0,x1,15); tfround(x0,x1,26); tfround(x0,x1,6);
  x0 += k1; x1 += k2 + 1u;
  tfround(x0,x1,17); tfround(x0,x1,29); tfround(x0,x1,16); tfround(x0,x1,24);
  x0 += k2; x1 += k0 + 2u;
  tfround(x0,x1,13); tfround(x0,x1,15); tfround(x0,x1,26); tfround(x0,x1,6);
  x0 += k0; x1 += k1 + 3u;
  tfround(x0,x1,17); tfround(x0,x1,29); tfround(x0,x1,16); tfround(x0,x1,24);
  x0 += k1; x1 += k2 + 4u;
  tfround(x0,x1,13); tfround(x0,x1,15); tfround(x0,x1,26); tfround(x0,x1,6);
  x0 += k2; x1 += k0 + 5u;
}

// jax.random.uniform bit pattern: (bits>>9 | 0x3F800000) bitcast - 1.0
__device__ __forceinline__ float u01(uint32_t bits) {
  return __uint_as_float((bits >> 9) | 0x3F800000u) - 1.0f;
}

// PARTITIONABLE threefry (modern JAX default):
// split(key(42), 32): key_r = full output pair of threefry((0,42), x0=0, x1=r).
// keys[2r] = o0, keys[2r+1] = o1.
__global__ __launch_bounds__(64) void setup_keys(uint32_t* keys) {
  int r = threadIdx.x;
  if (r < 32) {
    uint32_t x0 = 0u, x1 = (uint32_t)r;
    threefry2x32(0u, 42u, x0, x1);
    keys[2 * r]     = x0;
    keys[2 * r + 1] = x1;
  }
}

// ============================ f32 GEMM ======================================
// C[M,N] = act(A[M,K] @ W[K,N] + bias). 128x128 tile, BK=8, 256 thr, 8x8/thread.
// Requires M%128==0, K%8==0 (true for all call sites). N bounds-checked.
#define BM 128
#define BN 128
#define BKK 8
__global__ __launch_bounds__(256)
void gemm_f32(const float* __restrict__ A, const float* __restrict__ W,
              const float* __restrict__ bias, float* __restrict__ C,
              int M, int N, int K, int relu) {
  __shared__ float As[BKK][BM + 4];
  __shared__ float Ws[BKK][BN + 4];
  const int t = threadIdx.x;
  const int row0 = blockIdx.y * BM;
  const int col0 = blockIdx.x * BN;
  const int tx = t & 15, ty = t >> 4;
  float acc[8][8] = {};

  for (int k0 = 0; k0 < K; k0 += BKK) {
    { // A tile: 128 rows x 8 k ; thread loads float4
      int m = t >> 1, kk4 = (t & 1) * 4;
      const float* src = A + (size_t)(row0 + m) * K + k0 + kk4;
      float4 v = *(const float4*)src;
      As[kk4 + 0][m] = v.x; As[kk4 + 1][m] = v.y;
      As[kk4 + 2][m] = v.z; As[kk4 + 3][m] = v.w;
    }
    { // W tile: 8 k x 128 cols
      int kk = t >> 5, c = (t & 31) * 4;
      int gc = col0 + c;
      const float* src = W + (size_t)(k0 + kk) * N + gc;
      if (gc + 3 < N) {
        float4 v = *(const float4*)src;
        Ws[kk][c] = v.x; Ws[kk][c + 1] = v.y; Ws[kk][c + 2] = v.z; Ws[kk][c + 3] = v.w;
      } else {
        #pragma unroll
        for (int j = 0; j < 4; ++j) Ws[kk][c + j] = (gc + j < N) ? src[j] : 0.0f;
      }
    }
    __syncthreads();
    #pragma unroll
    for (int kk = 0; kk < BKK; ++kk) {
      float a[8], w[8];
      #pragma unroll
      for (int i = 0; i < 8; ++i) a[i] = As[kk][ty * 8 + i];
      #pragma unroll
      for (int j = 0; j < 8; ++j) w[j] = Ws[kk][tx * 8 + j];
      #pragma unroll
      for (int i = 0; i < 8; ++i)
        #pragma unroll
        for (int j = 0; j < 8; ++j)
          acc[i][j] = fmaf(a[i], w[j], acc[i][j]);
    }
    __syncthreads();
  }

  for (int i = 0; i < 8; ++i) {
    int m = row0 + ty * 8 + i;
    float* crow = C + (size_t)m * N;
    for (int j = 0; j < 8; ++j) {
      int n = col0 + tx * 8 + j;
      if (n < N) {
        float v = acc[i][j] + bias[n];
        if (relu) v = fmaxf(v, 0.0f);
        crow[n] = v;
      }
    }
  }
}

// ============================ kappa head ====================================
// kappa = softplus(h @ conc_w + conc_b) + 1 ; softplus = max(x,0)+log1p(exp(-|x|))
__global__ __launch_bounds__(256)
void kappa_kernel(const float* __restrict__ h, const float* __restrict__ conc_w,
                  const float* __restrict__ conc_b, float* __restrict__ kap,
                  int Brows, int K) {
  int row = blockIdx.x * 4 + (threadIdx.x >> 6);
  int lane = threadIdx.x & 63;
  if (row >= Brows) return;
  const float* hr = h + (size_t)row * K;
  float s = 0.0f;
  for (int i = lane; i < K; i += 64) s += hr[i] * conc_w[i];
  for (int off = 32; off > 0; off >>= 1) s += __shfl_down(s, off, 64);
  if (lane == 0) {
    float x = s + conc_b[0];
    float sp = fmaxf(x, 0.0f) + log1pf(expf(-fabsf(x)));
    kap[row] = sp + 1.0f;
  }
}

// ============================ von Mises sampler =============================
__device__ __forceinline__ float best_r_of(float kap) {
  float tau = 1.0f + sqrtf(1.0f + (4.0f * kap) * kap);
  float rho = (tau - sqrtf(2.0f * tau)) / (2.0f * kap);
  return (1.0f + rho * rho) / (2.0f * rho);
}

__device__ __forceinline__ void vm_step(float &theta, bool &done, float kap,
                                        float r, float u1, float u2, float u3) {
  float zc = cosf(PI_F * u1);
  float f = (1.0f + r * zc) / (r + zc);
  float c = kap * (r - f);
  bool acc1 = (c * (2.0f - c) - u2) > 0.0f;
  bool acc2 = ((logf(c / u2) + 1.0f) - c) >= 0.0f;
  if (acc1 || acc2) {
    float fcl = fminf(fmaxf(f, -1.0f), 1.0f);
    float sg = (u3 > 0.5f) ? 1.0f : ((u3 < 0.5f) ? -1.0f : 0.0f);
    theta = sg * acosf(fcl);
    done = true;
  }
}

__device__ __forceinline__ float wrap_theta(float th, float loc) {
  float y = (th + loc) + PI_F;
  float m = fmodf(y, TWO_PI_F);
  if (m < 0.0f) m += TWO_PI_F;
  return m - PI_F;
}

// PARTITIONABLE uniform(k,(3,16384,64)): flat element i gets bits from block
// threefry(k, x0=hi32(i)=0, x1=i), bits = o0 ^ o1.
// Element e of theta: u1 at i=e, u2 at i=1048576+e, u3 at i=2097152+e.
__global__ __launch_bounds__(256)
void vonmises_kernel(const float* __restrict__ mu, const float* __restrict__ kap,
                     const uint32_t* __restrict__ keys, float* __restrict__ theta_out) {
  __shared__ uint32_t kk[64];
  if (threadIdx.x < 64) kk[threadIdx.x] = keys[threadIdx.x];
  __syncthreads();

  uint32_t e = blockIdx.x * 256u + threadIdx.x;   // [0, 1048576)
  int z = (int)(e & 63u);
  bool live = (z != 0);   // theta[:,0] is never consumed downstream

  float kap1 = kap[e >> 6];
  float r1 = best_r_of(kap1);
  float th1 = 0.0f;
  bool done = !live;

  for (int rd = 0; rd < 32; ++rd) {
    if (__all(done)) break;
    uint32_t K0 = kk[2 * rd], K1 = kk[2 * rd + 1];
    uint32_t a0 = 0u, a1 = e;
    uint32_t b0 = 0u, b1 = e + 1048576u;
    uint32_t c0 = 0u, c1 = e + 2097152u;
    threefry2x32(K0, K1, a0, a1);
    threefry2x32(K0, K1, b0, b1);
    threefry2x32(K0, K1, c0, c1);
    if (!done) {
      float u1 = u01(a0 ^ a1);
      float u2 = u01(b0 ^ b1);
      float u3 = u01(c0 ^ c1);
      vm_step(th1, done, kap1, r1, u1, u2, u3);
    }
  }
  if (live) {
    theta_out[e] = wrap_theta(th1, mu[e]);
  }
}

// ===================== real iDFT (ortho) + pre layer ========================
// Re z_c[n] = (1+(-1)^n)/sqrt(128) + (2/sqrt(128)) * sum_{k=1}^{63} cos(theta_k + 2pi k n/128)
// Im z_c == 0 (conjugate-symmetric spectrum). z[j] = sum_n ReZ[n]*pre_w[2n,j] + pre_b[j]
__global__ __launch_bounds__(128)
void dft_pre_kernel(const float* __restrict__ theta, const float* __restrict__ pre_w,
                    const float* __restrict__ pre_b, float* __restrict__ z_out) {
  __shared__ float ct[128], st[128], cs[64], ss[64], rez[128];
  const int b = blockIdx.x;
  const int t = threadIdx.x;  // 128 threads
  {
    float a = (float)t * 0.015625f;      // t/64
    ct[t] = cospif(a);
    st[t] = sinpif(a);
  }
  if (t >= 1 && t < 64) {
    float th = theta[(size_t)b * 64 + t];
    cs[t] = cosf(th);
    ss[t] = sinf(th);
  }
  __syncthreads();
  {
    float acc = 0.0f;
    #pragma unroll 1
    for (int k = 1; k < 64; ++k) {
      int idx = (k * t) & 127;
      acc = fmaf(cs[k], ct[idx], acc);
      acc = fmaf(-ss[k], st[idx], acc);
    }
    const float inv = 0.08838834764831845f;  // 1/sqrt(128)
    float base = (t & 1) ? 0.0f : 2.0f * inv;
    rez[t] = fmaf(2.0f * inv, acc, base);
  }
  __syncthreads();
  if (t < 64) {
    float acc = pre_b[t];
    #pragma unroll 4
    for (int n = 0; n < 128; ++n)
      acc = fmaf(rez[n], pre_w[n * 128 + t], acc);   // pre_w[(2n)*64 + t]
    z_out[(size_t)b * 64 + t] = acc;
  }
}

// ============================ launch ========================================
extern "C" void kernel_launch(void* const* d_in, const int* in_sizes, int n_in,
                              void* d_out, int out_size, void* d_ws, size_t ws_size,
                              hipStream_t stream) {
  const float* x      = (const float*)d_in[0];
  const float* enc_w1 = (const float*)d_in[1];
  const float* enc_b1 = (const float*)d_in[2];
  const float* enc_w2 = (const float*)d_in[3];
  const float* enc_b2 = (const float*)d_in[4];
  const float* mu_w   = (const float*)d_in[5];
  const float* mu_b   = (const float*)d_in[6];
  const float* conc_w = (const float*)d_in[7];
  const float* conc_b = (const float*)d_in[8];
  const float* pre_w  = (const float*)d_in[9];
  const float* pre_b  = (const float*)d_in[10];
  const float* dec_w1 = (const float*)d_in[11];
  const float* dec_b1 = (const float*)d_in[12];
  const float* dec_w2 = (const float*)d_in[13];
  const float* dec_b2 = (const float*)d_in[14];
  const float* dec_w3 = (const float*)d_in[15];
  const float* dec_b3 = (const float*)d_in[16];

  float* out = (float*)d_out;
  float* mu_out  = out;                 // [16384,64]
  float* kap_out = out + 1048576;       // [16384,1]
  float* z_out   = out + 1064960;       // [16384,64]
  float* xr_out  = out + 2113536;       // [16384,784]

  float* ws = (float*)d_ws;
  float*    theta = ws;                               // 1,048,576 f
  uint32_t* keys  = (uint32_t*)(ws + 1048576);        // 64 u32
  float*    bufA  = ws + 1048704;                     // 33,554,432 f (h1 -> d2)
  float*    bufB  = bufA + 33554432;                  // 16,777,216 f (h  -> d1)

  setup_keys<<<1, 64, 0, stream>>>(keys);
  // encoder
  gemm_f32<<<dim3(16, 128), 256, 0, stream>>>(x,    enc_w1, enc_b1, bufA, 16384, 2048, 784, 1);
  gemm_f32<<<dim3(8, 128),  256, 0, stream>>>(bufA, enc_w2, enc_b2, bufB, 16384, 1024, 2048, 1);
  gemm_f32<<<dim3(1, 128),  256, 0, stream>>>(bufB, mu_w,   mu_b,   mu_out, 16384, 64, 1024, 0);
  kappa_kernel<<<4096, 256, 0, stream>>>(bufB, conc_w, conc_b, kap_out, 16384, 1024);
  // sampler + spectral reparameterization
  vonmises_kernel<<<4096, 256, 0, stream>>>(mu_out, kap_out, keys, theta);
  dft_pre_kernel<<<16384, 128, 0, stream>>>(theta, pre_w, pre_b, z_out);
  // decoder
  gemm_f32<<<dim3(8, 128),  256, 0, stream>>>(z_out, dec_w1, dec_b1, bufB, 16384, 1024, 64, 1);
  gemm_f32<<<dim3(16, 128), 256, 0, stream>>>(bufB,  dec_w2, dec_b2, bufA, 16384, 2048, 1024, 1);
  gemm_f32<<<dim3(7, 128),  256, 0, stream>>>(bufA,  dec_w3, dec_b3, xr_out, 16384, 784, 2048, 0);
}

// Round 4
// 1603.724 us; speedup vs baseline: 2.1203x; 2.1203x over previous
//
#include <hip/hip_runtime.h>
#include <hip/hip_bf16.h>
#include <stdint.h>

#pragma clang fp contract(off)

#define PI_F     3.14159265358979323846f
#define TWO_PI_F 6.28318530717958647692f

typedef short short8 __attribute__((ext_vector_type(8)));
typedef float f32x4  __attribute__((ext_vector_type(4)));

// ============================ threefry2x32 ==================================
__device__ __forceinline__ void tfround(uint32_t &x0, uint32_t &x1, const int r) {
  x0 += x1;
  x1 = (x1 << r) | (x1 >> (32 - r));
  x1 ^= x0;
}
__device__ __forceinline__ void threefry2x32(uint32_t k0, uint32_t k1,
                                             uint32_t &x0, uint32_t &x1) {
  uint32_t k2 = k0 ^ k1 ^ 0x1BD11BDAu;
  x0 += k0; x1 += k1;
  tfround(x0,x1,13); tfround(x0,x1,15); tfround(x0,x1,26); tfround(x0,x1,6);
  x0 += k1; x1 += k2 + 1u;
  tfround(x0,x1,17); tfround(x0,x1,29); tfround(x0,x1,16); tfround(x0,x1,24);
  x0 += k2; x1 += k0 + 2u;
  tfround(x0,x1,13); tfround(x0,x1,15); tfround(x0,x1,26); tfround(x0,x1,6);
  x0 += k0; x1 += k1 + 3u;
  tfround(x0,x1,17); tfround(x0,x1,29); tfround(x0,x1,16); tfround(x0,x1,24);
  x0 += k1; x1 += k2 + 4u;
  tfround(x0,x1,13); tfround(x0,x1,15); tfround(x0,x1,26); tfround(x0,x1,6);
  x0 += k2; x1 += k0 + 5u;
}
__device__ __forceinline__ float u01(uint32_t bits) {
  return __uint_as_float((bits >> 9) | 0x3F800000u) - 1.0f;
}
__global__ __launch_bounds__(64) void setup_keys(uint32_t* keys) {
  int r = threadIdx.x;
  if (r < 32) {
    uint32_t x0 = 0u, x1 = (uint32_t)r;
    threefry2x32(0u, 42u, x0, x1);
    keys[2 * r]     = x0;
    keys[2 * r + 1] = x1;
  }
}

// ====================== bf16 split helpers ==================================
__device__ __forceinline__ unsigned short bf16_rn(float v) {
  uint32_t u = __float_as_uint(v);
  return (unsigned short)((u + 0x7FFFu + ((u >> 16) & 1u)) >> 16);
}
__device__ __forceinline__ void split_bf16(float v, short &h, short &l) {
  unsigned short hb = bf16_rn(v);
  h = (short)hb;
  float hf = __uint_as_float(((uint32_t)hb) << 16);
  l = (short)bf16_rn(v - hf);
}

// f32 [R][C] -> bf16 hi/lo [R][Cp] (zero-padded cols)
__global__ __launch_bounds__(256)
void split_pad(const float* __restrict__ src, short* __restrict__ dh,
               short* __restrict__ dl, int C, int Cp) {
  int r = blockIdx.x;
  for (int c = threadIdx.x; c < Cp; c += blockDim.x) {
    float v = (c < C) ? src[(size_t)r * C + c] : 0.0f;
    short h, l; split_bf16(v, h, l);
    dh[(size_t)r * Cp + c] = h;
    dl[(size_t)r * Cp + c] = l;
  }
}

// f32 [K][N] -> transposed bf16 hi/lo [Np][Kp] (zero-padded)
__global__ __launch_bounds__(256)
void transpose_split(const float* __restrict__ src, short* __restrict__ dh,
                     short* __restrict__ dl, int K, int N, int Kp, int Np) {
  __shared__ float tile[32][33];
  int n0 = blockIdx.x * 32, k0 = blockIdx.y * 32;
  int tn = threadIdx.x & 31, tk4 = threadIdx.x >> 5;  // 8 groups of 4 rows
  #pragma unroll
  for (int i = 0; i < 4; ++i) {
    int k = k0 + tk4 * 4 + i;
    float v = (k < K && (n0 + tn) < N) ? src[(size_t)k * N + n0 + tn] : 0.0f;
    tile[tk4 * 4 + i][tn] = v;
  }
  __syncthreads();
  #pragma unroll
  for (int i = 0; i < 4; ++i) {
    int n = n0 + tk4 * 4 + i;
    int k = k0 + tn;
    if (n < Np && k < Kp) {
      float v = tile[tn][tk4 * 4 + i];
      short h, l; split_bf16(v, h, l);
      dh[(size_t)n * Kp + k] = h;
      dl[(size_t)n * Kp + k] = l;
    }
  }
}

// ====================== async global->LDS ===================================
__device__ __forceinline__ void async16(void* l, const void* g) {
  __builtin_amdgcn_global_load_lds(
      (const __attribute__((address_space(1))) void*)(uintptr_t)g,
      (__attribute__((address_space(3))) void*)(uint32_t)(uintptr_t)l,
      16, 0, 0);
}

// ====================== bf16x3 split MFMA GEMM ==============================
// C[M,Nout] = act(A @ Wt^T + bias), A=[M,Kp] hi/lo bf16, Wt=[Npad,Kp] hi/lo bf16.
// 128x128 tile, BK=32, 256 threads (4 waves, 2x2 of 64x64), 16x16x32 MFMA, split3.
// LDS layout per operand-half: [chunk(4)][row(128)] 16B slots, chunk-major.
// OUTMODE 0: f32 store (col-masked to Nout). OUTMODE 1: bf16 hi/lo pair store.
template<int RELU, int OUTMODE>
__global__ __launch_bounds__(256)
void gemm_mfma3(const short* __restrict__ Ah, const short* __restrict__ Al,
                const short* __restrict__ Bh, const short* __restrict__ Bl,
                const float* __restrict__ bias,
                float* __restrict__ Cf, short* __restrict__ Ch, short* __restrict__ Cl,
                int Kp, int NK, int Nout) {
  __shared__ short8 lds8[2048];   // 32 KiB: [op(4)][chunk(4)][row(128)]

  // XCD-aware block swizzle (all grids are multiples of 8)
  int gx = gridDim.x;
  int nwg = gx * gridDim.y;
  int bid = blockIdx.y * gx + blockIdx.x;
  int cpx = nwg >> 3;
  int swz = (bid & 7) * cpx + (bid >> 3);
  int tile_x = swz % gx, tile_y = swz / gx;

  const int row0 = tile_y * 128;
  const int col0 = tile_x * 128;
  const int t = threadIdx.x;
  const int lane = t & 63, w = t >> 6;
  const int wr = w >> 1, wc = w & 1;
  const int lrow = lane & 15, lch = lane >> 4;

  f32x4 acc[4][4] = {};

  auto stage = [&](int k0) {
    #pragma unroll
    for (int q = 0; q < 8; ++q) {
      int s = q * 256 + t;
      int op = s >> 9;          // uniform per q-pair
      int so = s & 511;
      int chunk = so >> 7, row = so & 127;
      const short* g;
      if (op == 0)      g = Ah + (size_t)(row0 + row) * Kp + k0 + chunk * 8;
      else if (op == 1) g = Al + (size_t)(row0 + row) * Kp + k0 + chunk * 8;
      else if (op == 2) g = Bh + (size_t)(col0 + row) * Kp + k0 + chunk * 8;
      else              g = Bl + (size_t)(col0 + row) * Kp + k0 + chunk * 8;
      short8* ldst = &lds8[q * 256 + w * 64];   // wave-uniform base; HW adds lane*16
      async16((void*)ldst, (const void*)g);
    }
  };

  stage(0);
  for (int ks = 0; ks < NK; ++ks) {
    __syncthreads();   // drains vmcnt(0): staged data visible

    short8 ah[4], al[4], bh[4], bl[4];
    #pragma unroll
    for (int mf = 0; mf < 4; ++mf) {
      int sa = lch * 128 + wr * 64 + mf * 16 + lrow;
      ah[mf] = lds8[sa];
      al[mf] = lds8[512 + sa];
    }
    #pragma unroll
    for (int nf = 0; nf < 4; ++nf) {
      int sb = lch * 128 + wc * 64 + nf * 16 + lrow;
      bh[nf] = lds8[1024 + sb];
      bl[nf] = lds8[1536 + sb];
    }
    #pragma unroll
    for (int mf = 0; mf < 4; ++mf)
      #pragma unroll
      for (int nf = 0; nf < 4; ++nf) {
        acc[mf][nf] = __builtin_amdgcn_mfma_f32_16x16x32_bf16(ah[mf], bh[nf], acc[mf][nf], 0, 0, 0);
        acc[mf][nf] = __builtin_amdgcn_mfma_f32_16x16x32_bf16(al[mf], bh[nf], acc[mf][nf], 0, 0, 0);
        acc[mf][nf] = __builtin_amdgcn_mfma_f32_16x16x32_bf16(ah[mf], bl[nf], acc[mf][nf], 0, 0, 0);
      }
    __syncthreads();
    if (ks + 1 < NK) stage((ks + 1) * 32);
  }

  // epilogue: C/D layout col=lane&15, row=(lane>>4)*4+reg
  #pragma unroll
  for (int mf = 0; mf < 4; ++mf)
    #pragma unroll
    for (int nf = 0; nf < 4; ++nf)
      #pragma unroll
      for (int j = 0; j < 4; ++j) {
        int grow = row0 + wr * 64 + mf * 16 + lch * 4 + j;
        int gcol = col0 + wc * 64 + nf * 16 + lrow;
        float v = acc[mf][nf][j];
        if (OUTMODE == 0) {
          if (gcol < Nout) {
            v += bias[gcol];
            if (RELU) v = fmaxf(v, 0.0f);
            Cf[(size_t)grow * Nout + gcol] = v;
          }
        } else {
          v += bias[gcol];
          if (RELU) v = fmaxf(v, 0.0f);
          short h, l; split_bf16(v, h, l);
          Ch[(size_t)grow * Nout + gcol] = h;
          Cl[(size_t)grow * Nout + gcol] = l;
        }
      }
}

// ============================ f32 GEMM (mu head) ============================
#define BKK 8
__global__ __launch_bounds__(256)
void gemm_f32(const float* __restrict__ A, const float* __restrict__ W,
              const float* __restrict__ bias, float* __restrict__ C,
              int M, int N, int K, int relu) {
  __shared__ float As[BKK][128 + 4];
  __shared__ float Ws[BKK][128 + 4];
  const int t = threadIdx.x;
  const int row0 = blockIdx.y * 128;
  const int col0 = blockIdx.x * 128;
  const int tx = t & 15, ty = t >> 4;
  float acc[8][8] = {};
  for (int k0 = 0; k0 < K; k0 += BKK) {
    {
      int m = t >> 1, kk4 = (t & 1) * 4;
      const float* src = A + (size_t)(row0 + m) * K + k0 + kk4;
      float4 v = *(const float4*)src;
      As[kk4 + 0][m] = v.x; As[kk4 + 1][m] = v.y;
      As[kk4 + 2][m] = v.z; As[kk4 + 3][m] = v.w;
    }
    {
      int kk = t >> 5, c = (t & 31) * 4;
      int gc = col0 + c;
      const float* src = W + (size_t)(k0 + kk) * N + gc;
      if (gc + 3 < N) {
        float4 v = *(const float4*)src;
        Ws[kk][c] = v.x; Ws[kk][c + 1] = v.y; Ws[kk][c + 2] = v.z; Ws[kk][c + 3] = v.w;
      } else {
        #pragma unroll
        for (int j = 0; j < 4; ++j) Ws[kk][c + j] = (gc + j < N) ? src[j] : 0.0f;
      }
    }
    __syncthreads();
    #pragma unroll
    for (int kk = 0; kk < BKK; ++kk) {
      float a[8], wv[8];
      #pragma unroll
      for (int i = 0; i < 8; ++i) a[i] = As[kk][ty * 8 + i];
      #pragma unroll
      for (int j = 0; j < 8; ++j) wv[j] = Ws[kk][tx * 8 + j];
      #pragma unroll
      for (int i = 0; i < 8; ++i)
        #pragma unroll
        for (int j = 0; j < 8; ++j)
          acc[i][j] = fmaf(a[i], wv[j], acc[i][j]);
    }
    __syncthreads();
  }
  for (int i = 0; i < 8; ++i) {
    int m = row0 + ty * 8 + i;
    float* crow = C + (size_t)m * N;
    for (int j = 0; j < 8; ++j) {
      int n = col0 + tx * 8 + j;
      if (n < N) {
        float v = acc[i][j] + bias[n];
        if (relu) v = fmaxf(v, 0.0f);
        crow[n] = v;
      }
    }
  }
}

// ============================ kappa head ====================================
__global__ __launch_bounds__(256)
void kappa_kernel(const float* __restrict__ h, const float* __restrict__ conc_w,
                  const float* __restrict__ conc_b, float* __restrict__ kap,
                  int Brows, int K) {
  int row = blockIdx.x * 4 + (threadIdx.x >> 6);
  int lane = threadIdx.x & 63;
  if (row >= Brows) return;
  const float* hr = h + (size_t)row * K;
  float s = 0.0f;
  for (int i = lane; i < K; i += 64) s += hr[i] * conc_w[i];
  for (int off = 32; off > 0; off >>= 1) s += __shfl_down(s, off, 64);
  if (lane == 0) {
    float x = s + conc_b[0];
    float sp = fmaxf(x, 0.0f) + log1pf(expf(-fabsf(x)));
    kap[row] = sp + 1.0f;
  }
}

// ============================ von Mises sampler =============================
__device__ __forceinline__ float best_r_of(float kap) {
  float tau = 1.0f + sqrtf(1.0f + (4.0f * kap) * kap);
  float rho = (tau - sqrtf(2.0f * tau)) / (2.0f * kap);
  return (1.0f + rho * rho) / (2.0f * rho);
}
__device__ __forceinline__ void vm_step(float &theta, bool &done, float kap,
                                        float r, float u1, float u2, float u3) {
  float zc = cosf(PI_F * u1);
  float f = (1.0f + r * zc) / (r + zc);
  float c = kap * (r - f);
  bool acc1 = (c * (2.0f - c) - u2) > 0.0f;
  bool acc2 = ((logf(c / u2) + 1.0f) - c) >= 0.0f;
  if (acc1 || acc2) {
    float fcl = fminf(fmaxf(f, -1.0f), 1.0f);
    float sg = (u3 > 0.5f) ? 1.0f : ((u3 < 0.5f) ? -1.0f : 0.0f);
    theta = sg * acosf(fcl);
    done = true;
  }
}
__device__ __forceinline__ float wrap_theta(float th, float loc) {
  float y = (th + loc) + PI_F;
  float m = fmodf(y, TWO_PI_F);
  if (m < 0.0f) m += TWO_PI_F;
  return m - PI_F;
}
__global__ __launch_bounds__(256)
void vonmises_kernel(const float* __restrict__ mu, const float* __restrict__ kap,
                     const uint32_t* __restrict__ keys, float* __restrict__ theta_out) {
  __shared__ uint32_t kk[64];
  if (threadIdx.x < 64) kk[threadIdx.x] = keys[threadIdx.x];
  __syncthreads();
  uint32_t e = blockIdx.x * 256u + threadIdx.x;
  int z = (int)(e & 63u);
  bool live = (z != 0);
  float kap1 = kap[e >> 6];
  float r1 = best_r_of(kap1);
  float th1 = 0.0f;
  bool done = !live;
  for (int rd = 0; rd < 32; ++rd) {
    if (__all(done)) break;
    uint32_t K0 = kk[2 * rd], K1 = kk[2 * rd + 1];
    uint32_t a0 = 0u, a1 = e;
    uint32_t b0 = 0u, b1 = e + 1048576u;
    uint32_t c0 = 0u, c1 = e + 2097152u;
    threefry2x32(K0, K1, a0, a1);
    threefry2x32(K0, K1, b0, b1);
    threefry2x32(K0, K1, c0, c1);
    if (!done) {
      vm_step(th1, done, kap1, r1, u01(a0 ^ a1), u01(b0 ^ b1), u01(c0 ^ c1));
    }
  }
  if (live) theta_out[e] = wrap_theta(th1, mu[e]);
}

// ===================== real iDFT (ortho) + pre layer ========================
__global__ __launch_bounds__(128)
void dft_pre_kernel(const float* __restrict__ theta, const float* __restrict__ pre_w,
                    const float* __restrict__ pre_b, float* __restrict__ z_out) {
  __shared__ float ct[128], st[128], cs[64], ss[64], rez[128];
  const int b = blockIdx.x;
  const int t = threadIdx.x;
  {
    float a = (float)t * 0.015625f;
    ct[t] = cospif(a);
    st[t] = sinpif(a);
  }
  if (t >= 1 && t < 64) {
    float th = theta[(size_t)b * 64 + t];
    cs[t] = cosf(th);
    ss[t] = sinf(th);
  }
  __syncthreads();
  {
    float acc = 0.0f;
    #pragma unroll 1
    for (int k = 1; k < 64; ++k) {
      int idx = (k * t) & 127;
      acc = fmaf(cs[k], ct[idx], acc);
      acc = fmaf(-ss[k], st[idx], acc);
    }
    const float inv = 0.08838834764831845f;
    float base = (t & 1) ? 0.0f : 2.0f * inv;
    rez[t] = fmaf(2.0f * inv, acc, base);
  }
  __syncthreads();
  if (t < 64) {
    float acc = pre_b[t];
    #pragma unroll 4
    for (int n = 0; n < 128; ++n)
      acc = fmaf(rez[n], pre_w[n * 128 + t], acc);
    z_out[(size_t)b * 64 + t] = acc;
  }
}

// ============================ launch ========================================
extern "C" void kernel_launch(void* const* d_in, const int* in_sizes, int n_in,
                              void* d_out, int out_size, void* d_ws, size_t ws_size,
                              hipStream_t stream) {
  const float* x      = (const float*)d_in[0];
  const float* enc_w1 = (const float*)d_in[1];
  const float* enc_b1 = (const float*)d_in[2];
  const float* enc_w2 = (const float*)d_in[3];
  const float* enc_b2 = (const float*)d_in[4];
  const float* mu_w   = (const float*)d_in[5];
  const float* mu_b   = (const float*)d_in[6];
  const float* conc_w = (const float*)d_in[7];
  const float* conc_b = (const float*)d_in[8];
  const float* pre_w  = (const float*)d_in[9];
  const float* pre_b  = (const float*)d_in[10];
  const float* dec_w1 = (const float*)d_in[11];
  const float* dec_b1 = (const float*)d_in[12];
  const float* dec_w2 = (const float*)d_in[13];
  const float* dec_b2 = (const float*)d_in[14];
  const float* dec_w3 = (const float*)d_in[15];
  const float* dec_b3 = (const float*)d_in[16];

  float* out = (float*)d_out;
  float* mu_out  = out;                 // [16384,64]
  float* kap_out = out + 1048576;       // [16384,1]
  float* z_out   = out + 1064960;       // [16384,64]
  float* xr_out  = out + 2113536;       // [16384,784]

  // ---- workspace layout (bytes) ----
  char* ws = (char*)d_ws;
  size_t o = 0;
  auto alloc = [&](size_t bytes) { size_t r = o; o += (bytes + 1023) & ~(size_t)1023; return r; };
  uint32_t* keys  = (uint32_t*)(ws + alloc(256));
  float*    theta = (float*)(ws + alloc(4194304));
  short* w1t_h = (short*)(ws + alloc((size_t)2048 * 800 * 2));
  short* w1t_l = (short*)(ws + alloc((size_t)2048 * 800 * 2));
  short* w2t_h = (short*)(ws + alloc((size_t)1024 * 2048 * 2));
  short* w2t_l = (short*)(ws + alloc((size_t)1024 * 2048 * 2));
  short* dw1t_h = (short*)(ws + alloc((size_t)1024 * 64 * 2));
  short* dw1t_l = (short*)(ws + alloc((size_t)1024 * 64 * 2));
  short* dw2t_h = (short*)(ws + alloc((size_t)2048 * 1024 * 2));
  short* dw2t_l = (short*)(ws + alloc((size_t)2048 * 1024 * 2));
  short* dw3t_h = (short*)(ws + alloc((size_t)896 * 2048 * 2));
  short* dw3t_l = (short*)(ws + alloc((size_t)896 * 2048 * 2));
  short* zh = (short*)(ws + alloc((size_t)16384 * 64 * 2));
  short* zl = (short*)(ws + alloc((size_t)16384 * 64 * 2));
  char* region1 = ws + alloc((size_t)2 * 16384 * 2048 * 2);  // h1 pair / d2 pair
  char* region2 = ws + alloc((size_t)16384 * 1024 * 4);      // x pair -> h f32 -> d1 pair
  (void)ws_size;

  short* h1h = (short*)region1;
  short* h1l = (short*)(region1 + (size_t)16384 * 2048 * 2);
  short* d2h = h1h;  short* d2l = h1l;
  short* xh = (short*)region2;
  short* xl = (short*)(region2 + (size_t)16384 * 800 * 2);
  float* hbuf = (float*)region2;
  short* d1h = (short*)region2;
  short* d1l = (short*)(region2 + (size_t)16384 * 1024 * 2);

  setup_keys<<<1, 64, 0, stream>>>(keys);

  // ---- conversions (weights + x) ----
  split_pad<<<16384, 256, 0, stream>>>(x, xh, xl, 784, 800);
  transpose_split<<<dim3(64, 25), 256, 0, stream>>>(enc_w1, w1t_h, w1t_l, 784, 2048, 800, 2048);
  transpose_split<<<dim3(32, 64), 256, 0, stream>>>(enc_w2, w2t_h, w2t_l, 2048, 1024, 2048, 1024);
  transpose_split<<<dim3(32, 2),  256, 0, stream>>>(dec_w1, dw1t_h, dw1t_l, 64, 1024, 64, 1024);
  transpose_split<<<dim3(64, 32), 256, 0, stream>>>(dec_w2, dw2t_h, dw2t_l, 1024, 2048, 1024, 2048);
  transpose_split<<<dim3(28, 64), 256, 0, stream>>>(dec_w3, dw3t_h, dw3t_l, 2048, 784, 2048, 896);

  // ---- encoder ----
  gemm_mfma3<1, 1><<<dim3(16, 128), 256, 0, stream>>>(xh, xl, w1t_h, w1t_l, enc_b1,
      nullptr, h1h, h1l, 800, 25, 2048);
  gemm_mfma3<1, 0><<<dim3(8, 128), 256, 0, stream>>>(h1h, h1l, w2t_h, w2t_l, enc_b2,
      hbuf, nullptr, nullptr, 2048, 64, 1024);
  gemm_f32<<<dim3(1, 128), 256, 0, stream>>>(hbuf, mu_w, mu_b, mu_out, 16384, 64, 1024, 0);
  kappa_kernel<<<4096, 256, 0, stream>>>(hbuf, conc_w, conc_b, kap_out, 16384, 1024);

  // ---- sampler + spectral reparameterization ----
  vonmises_kernel<<<4096, 256, 0, stream>>>(mu_out, kap_out, keys, theta);
  dft_pre_kernel<<<16384, 128, 0, stream>>>(theta, pre_w, pre_b, z_out);
  split_pad<<<16384, 256, 0, stream>>>(z_out, zh, zl, 64, 64);

  // ---- decoder ----
  gemm_mfma3<1, 1><<<dim3(8, 128), 256, 0, stream>>>(zh, zl, dw1t_h, dw1t_l, dec_b1,
      nullptr, d1h, d1l, 64, 2, 1024);
  gemm_mfma3<1, 1><<<dim3(16, 128), 256, 0, stream>>>(d1h, d1l, dw2t_h, dw2t_l, dec_b2,
      nullptr, d2h, d2l, 1024, 32, 2048);
  gemm_mfma3<0, 0><<<dim3(7, 128), 256, 0, stream>>>(d2h, d2l, dw3t_h, dw3t_l, dec_b3,
      xr_out, nullptr, nullptr, 2048, 64, 784);
}